// Round 10
// baseline (5483.937 us; speedup 1.0000x reference)
//
#include <hip/hip_runtime.h>
#include <math.h>

#define BATCH 4096
#define NIN   4096
#define NOUT  4096

#define BM 128
#define BN 64
#define BK 16
#define NSTAGE (NIN / BK)      // 256
#define FOLD_STAGES 32         // 32 * 16 = 512-element panels (R9-verified ORDER — do not touch)

// ---- numerics frozen by R9 (PASS, absmax 0.0625): ----
// f32 term chain (CR powf via double exp10), ascending-k fmaf chains,
// panel fold every 512 k, f32 epilogue. Any change breaks bit-exactness.
__device__ __forceinline__ float2 compute_terms(float xv) {
    float h  = (float)exp10(-(double)xv);
    float oh = 1e-14f / h;
    return make_float2(h * 0.1f, oh * 0.1f);
}

__global__ __launch_bounds__(256) void precompute_terms(const float* __restrict__ x,
                                                        float2* __restrict__ a2, int n) {
    int stride = gridDim.x * blockDim.x;
    for (int i = blockIdx.x * blockDim.x + threadIdx.x; i < n; i += stride)
        a2[i] = compute_terms(x[i]);
}

#define GLOAD16(g, l)                                                        \
    __builtin_amdgcn_global_load_lds(                                        \
        (const __attribute__((address_space(1))) void*)(g),                  \
        (__attribute__((address_space(3))) void*)(l), 16, 0, 0)

// Double-buffered, 1-barrier-per-stage GEMM pair.
// As[m][k] LINEAR (global_load_lds dest must be linear: lane l -> row l/8,
// col-pair 2*(l&7), 16B contiguous source). Bs reg-staged (sign conversion),
// written to next buffer AFTER compute (T14: HBM latency hides under FMAs).
__global__ __launch_bounds__(256, 4) void acid_gemm_dbuf(const float2* __restrict__ A2,
                                                         const float* __restrict__ W,
                                                         float* __restrict__ out) {
    __shared__ float2 As[2][BM][BK];   // 2 x 16 KiB
    __shared__ float  Bs[2][BK][BN];   // 2 x 4 KiB   (total 40960 B -> 4 blocks/CU)

    const int tid  = threadIdx.x;
    const int tx   = tid & 15;        // cols tx*4..+3
    const int ty   = tid >> 4;        // rows ty*8..+7
    const int lane = tid & 63;
    const int wid  = tid >> 6;
    const int bm0  = blockIdx.y * BM;
    const int bn0  = blockIdx.x * BN;

    // A staging geometry: per round r (4 rounds), wave w covers rows r*32+w*8..+7
    const int srow = wid * 8 + (lane >> 3);
    const int scol = (lane & 7) * 2;                       // float2 elements
    const float2* abase = A2 + (size_t)(bm0 + srow) * NIN + scol;

    // B staging geometry: thread t handles (k = t>>6 + 4r, c = t&63)
    const int bc = tid & 63;
    const int bkr = tid >> 6;

    float ma[8][4] = {}, mb[8][4] = {};   // panel-folded C accs
    float ca[8][4] = {}, cb[8][4] = {};   // in-panel ascending-k chains
    float wr[4];

    // prologue: stage s=0 into buf 0
    {
        char* lb = (char*)&As[0][0][0] + wid * 1024;
        #pragma unroll
        for (int r = 0; r < 4; ++r)
            GLOAD16(abase + (size_t)r * 32 * NIN, lb + r * 4096);
        const float* wp = W + (size_t)bkr * NOUT + bn0 + bc;
        #pragma unroll
        for (int t = 0; t < 4; ++t) wr[t] = wp[(size_t)t * 4 * NOUT];
        #pragma unroll
        for (int t = 0; t < 4; ++t) {
            float wv = wr[t];
            Bs[0][bkr + 4 * t][bc] = (wv > 0.f) ? 1.f : ((wv < 0.f) ? -1.f : 0.f);
        }
    }
    __syncthreads();

    int cur = 0;
    for (int s = 0; s < NSTAGE; ++s) {
        // prefetch stage s+1 into buf cur^1 (A direct-to-LDS; W to regs)
        if (s + 1 < NSTAGE) {
            char* lb = (char*)&As[cur ^ 1][0][0] + wid * 1024;
            const float2* g = abase + (size_t)(s + 1) * BK;
            #pragma unroll
            for (int r = 0; r < 4; ++r)
                GLOAD16(g + (size_t)r * 32 * NIN, lb + r * 4096);
            const float* wp = W + (size_t)((s + 1) * BK + bkr) * NOUT + bn0 + bc;
            #pragma unroll
            for (int t = 0; t < 4; ++t) wr[t] = wp[(size_t)t * 4 * NOUT];
        }

        // compute: 16 ascending k, chain order identical to R9
        #pragma unroll
        for (int k = 0; k < BK; ++k) {
            float2 av[8];
            float  sv[4];
            #pragma unroll
            for (int m = 0; m < 8; ++m) av[m] = As[cur][ty * 8 + m][k];
            #pragma unroll
            for (int n = 0; n < 4; ++n) sv[n] = Bs[cur][k][tx * 4 + n];
            #pragma unroll
            for (int m = 0; m < 8; ++m)
                #pragma unroll
                for (int n = 0; n < 4; ++n) {
                    ca[m][n] = fmaf(av[m].x, sv[n], ca[m][n]);
                    cb[m][n] = fmaf(av[m].y, sv[n], cb[m][n]);
                }
        }

        // panel boundary every 512 k: C += panel_acc (one f32 add)
        if (((s + 1) & (FOLD_STAGES - 1)) == 0) {
            #pragma unroll
            for (int m = 0; m < 8; ++m)
                #pragma unroll
                for (int n = 0; n < 4; ++n) {
                    ma[m][n] += ca[m][n]; ca[m][n] = 0.f;
                    mb[m][n] += cb[m][n]; cb[m][n] = 0.f;
                }
        }

        // write next B tile (waits on wr loads; hidden under the FMAs above)
        if (s + 1 < NSTAGE) {
            #pragma unroll
            for (int t = 0; t < 4; ++t) {
                float wv = wr[t];
                Bs[cur ^ 1][bkr + 4 * t][bc] = (wv > 0.f) ? 1.f : ((wv < 0.f) ? -1.f : 0.f);
            }
        }
        __syncthreads();   // drains vmcnt+lgkmcnt: As/Bs[cur^1] ready for all
        cur ^= 1;
    }

    // np f32 epilogue (frozen)
    #pragma unroll
    for (int m = 0; m < 8; ++m) {
        int row = bm0 + ty * 8 + m;
        #pragma unroll
        for (int n = 0; n < 4; ++n) {
            int col = bn0 + tx * 4 + n;
            float r    = ma[m][n] - mb[m][n];
            float conc = fabsf(r) / 409.6f;
            float hc   = (r < 0.f) ? (1e-14f / conc) : conc;
            float ph   = (-logf(hc)) / 2.302585092994046f;
            out[(size_t)row * NOUT + col] = ph;
        }
    }
}

// Fallback (ws too small): R9's proven kernel, on-the-fly terms.
__global__ __launch_bounds__(256, 2) void acid_gemm_fly(const float* __restrict__ X,
                                                        const float* __restrict__ W,
                                                        float* __restrict__ out) {
    __shared__ float2 Asf[32][BM + 1];
    __shared__ float  Bsf[32][BN];
    const int tid = threadIdx.x;
    const int tx = tid & 15, ty = tid >> 4;
    const int bm0 = blockIdx.y * BM, bn0 = blockIdx.x * BN;
    float ma[8][4] = {}, mb[8][4] = {}, ca[8][4] = {}, cb[8][4] = {};
    for (int s = 0; s < NIN / 32; ++s) {
        const int k0 = s * 32;
        for (int idx = tid; idx < BM * 32; idx += 256) {
            int m = idx >> 5, k = idx & 31;
            Asf[k][m] = compute_terms(X[(size_t)(bm0 + m) * NIN + k0 + k]);
        }
        for (int idx = tid; idx < 32 * BN; idx += 256) {
            int k = idx >> 6, c = idx & 63;
            float wv = W[(size_t)(k0 + k) * NOUT + bn0 + c];
            Bsf[k][c] = (wv > 0.f) ? 1.f : ((wv < 0.f) ? -1.f : 0.f);
        }
        __syncthreads();
        #pragma unroll 4
        for (int k = 0; k < 32; ++k) {
            float2 av[8]; float sv[4];
            #pragma unroll
            for (int m = 0; m < 8; ++m) av[m] = Asf[k][ty * 8 + m];
            #pragma unroll
            for (int n = 0; n < 4; ++n) sv[n] = Bsf[k][tx * 4 + n];
            #pragma unroll
            for (int m = 0; m < 8; ++m)
                #pragma unroll
                for (int n = 0; n < 4; ++n) {
                    ca[m][n] = fmaf(av[m].x, sv[n], ca[m][n]);
                    cb[m][n] = fmaf(av[m].y, sv[n], cb[m][n]);
                }
        }
        if ((((s + 1) * 32) & 511) == 0) {
            #pragma unroll
            for (int m = 0; m < 8; ++m)
                #pragma unroll
                for (int n = 0; n < 4; ++n) {
                    ma[m][n] += ca[m][n]; ca[m][n] = 0.f;
                    mb[m][n] += cb[m][n]; cb[m][n] = 0.f;
                }
        }
        __syncthreads();
    }
    #pragma unroll
    for (int m = 0; m < 8; ++m) {
        int row = bm0 + ty * 8 + m;
        #pragma unroll
        for (int n = 0; n < 4; ++n) {
            int col = bn0 + tx * 4 + n;
            float r = ma[m][n] - mb[m][n];
            float conc = fabsf(r) / 409.6f;
            float hc = (r < 0.f) ? (1e-14f / conc) : conc;
            out[(size_t)row * NOUT + col] = (-logf(hc)) / 2.302585092994046f;
        }
    }
}

extern "C" void kernel_launch(void* const* d_in, const int* in_sizes, int n_in,
                              void* d_out, int out_size, void* d_ws, size_t ws_size,
                              hipStream_t stream) {
    const float* x = (const float*)d_in[0];
    const float* w = (const float*)d_in[1];
    float* out = (float*)d_out;

    const size_t needA = (size_t)BATCH * NIN * sizeof(float2);  // 134.2 MB
    dim3 grid(NOUT / BN, BATCH / BM);

    if (ws_size >= needA) {
        float2* a2 = (float2*)d_ws;
        precompute_terms<<<4096, 256, 0, stream>>>(x, a2, BATCH * NIN);
        acid_gemm_dbuf<<<grid, dim3(256), 0, stream>>>(a2, w, out);
    } else {
        acid_gemm_fly<<<grid, dim3(256), 0, stream>>>(x, w, out);
    }
}

// Round 11
// 3466.076 us; speedup vs baseline: 1.5822x; 1.5822x over previous
//
#include <hip/hip_runtime.h>
#include <math.h>

#define BATCH 4096
#define NIN   4096
#define NOUT  4096

#define BM 128
#define BN 64
#define BK 32
#define NSTAGE (NIN / BK)        // 128
// R9-verified ORDER (frozen): [512x8] k-panels, single ascending fmaf chain,
// fold every 16 stages (16*32 = 512), f32 epilogue. Do not touch.

__device__ __forceinline__ float2 compute_terms(float xv) {
    float h  = (float)exp10(-(double)xv);
    float oh = 1e-14f / h;
    return make_float2(h * 0.1f, oh * 0.1f);
}

__global__ __launch_bounds__(256) void precompute_terms(const float* __restrict__ x,
                                                        float2* __restrict__ a2, int n) {
    int stride = gridDim.x * blockDim.x;
    for (int i = blockIdx.x * blockDim.x + threadIdx.x; i < n; i += stride)
        a2[i] = compute_terms(x[i]);
}

__device__ __forceinline__ float signf_of(float wv) {
    return (wv > 0.f) ? 1.f : ((wv < 0.f) ? -1.f : 0.f);
}

// R9 structure + T14 async-STAGE split:
//   issue s+1 global loads (regs) BEFORE compute of s  -> latency hides under 2048 fmaf
//   after compute + barrier: reg->LDS writes only      -> exposed window ~200 cyc
// LDS layout identical to R9 (As[k][m] f2, +1 pad row): reads measured conflict-free.
__global__ __launch_bounds__(256, 2) void acid_gemm_t14(const float2* __restrict__ A2,
                                                        const float* __restrict__ W,
                                                        float* __restrict__ out) {
    __shared__ float2 As[BK][BM + 1];   // [32][129] f2 = 33024 B
    __shared__ float  Bs[BK][BN];       // [32][64]  f32 = 8192 B

    const int tid = threadIdx.x;
    const int tx  = tid & 15;     // cols tx*4..+3
    const int ty  = tid >> 4;     // rows ty*8..+7
    const int bm0 = blockIdx.y * BM;
    const int bn0 = blockIdx.x * BN;

    // A staging: thread covers rows m0+16r (r=0..7), f4-col ac (k = 2*ac, 2*ac+1)
    const int m0 = tid >> 4;      // 0..15
    const int ac = tid & 15;      // f4 col within 32-k tile
    // W staging: thread covers k rows kw0+16r (r=0..1), f4-col wc (cols 4*wc..+3)
    const int kw0 = tid >> 4;
    const int wc  = tid & 15;

    float ma[8][4] = {}, mb[8][4] = {};   // C accs (panel-folded)
    float ca[8][4] = {}, cb[8][4] = {};   // in-panel ascending-k chains
    float4 areg[8], wreg[2];

    #define ISSUE_LOADS(s)                                                          \
        {                                                                           \
            const int k0_ = (s) * BK;                                               \
            _Pragma("unroll")                                                       \
            for (int r = 0; r < 8; ++r) {                                           \
                const float4* p = (const float4*)(A2 +                              \
                    (size_t)(bm0 + m0 + 16 * r) * NIN + k0_);                       \
                areg[r] = p[ac];                                                    \
            }                                                                       \
            _Pragma("unroll")                                                       \
            for (int r = 0; r < 2; ++r) {                                           \
                const float4* p = (const float4*)(W +                               \
                    (size_t)(k0_ + kw0 + 16 * r) * NOUT + bn0);                     \
                wreg[r] = p[wc];                                                    \
            }                                                                       \
        }

    #define WRITE_LDS()                                                             \
        {                                                                           \
            _Pragma("unroll")                                                       \
            for (int r = 0; r < 8; ++r) {                                           \
                int m = m0 + 16 * r;                                                \
                As[2 * ac][m]     = make_float2(areg[r].x, areg[r].y);              \
                As[2 * ac + 1][m] = make_float2(areg[r].z, areg[r].w);              \
            }                                                                       \
            _Pragma("unroll")                                                       \
            for (int r = 0; r < 2; ++r) {                                           \
                int k = kw0 + 16 * r;                                               \
                float4 wv = wreg[r];                                                \
                *(float4*)&Bs[k][4 * wc] = make_float4(                             \
                    signf_of(wv.x), signf_of(wv.y), signf_of(wv.z), signf_of(wv.w));\
            }                                                                       \
        }

    // prologue: stage 0
    ISSUE_LOADS(0);
    WRITE_LDS();
    __syncthreads();

    for (int s = 0; s < NSTAGE; ++s) {
        if (s + 1 < NSTAGE) ISSUE_LOADS(s + 1);   // in flight across the compute

        // compute: 32 ascending k, chain order identical to R9 (bit-exact)
        #pragma unroll 4
        for (int k = 0; k < BK; ++k) {
            float2 av[8];
            float  sv[4];
            #pragma unroll
            for (int m = 0; m < 8; ++m) av[m] = As[k][ty * 8 + m];
            #pragma unroll
            for (int n = 0; n < 4; ++n) sv[n] = Bs[k][tx * 4 + n];
            #pragma unroll
            for (int m = 0; m < 8; ++m)
                #pragma unroll
                for (int n = 0; n < 4; ++n) {
                    ca[m][n] = fmaf(av[m].x, sv[n], ca[m][n]);
                    cb[m][n] = fmaf(av[m].y, sv[n], cb[m][n]);
                }
        }

        // panel boundary every 512 k: C += panel_acc (one f32 add)
        if (((s + 1) & 15) == 0) {
            #pragma unroll
            for (int m = 0; m < 8; ++m)
                #pragma unroll
                for (int n = 0; n < 4; ++n) {
                    ma[m][n] += ca[m][n]; ca[m][n] = 0.f;
                    mb[m][n] += cb[m][n]; cb[m][n] = 0.f;
                }
        }

        __syncthreads();                       // all waves done READING As/Bs
        if (s + 1 < NSTAGE) WRITE_LDS();       // cheap reg->LDS (loads long done)
        __syncthreads();                       // tile ready
    }

    // np f32 epilogue (frozen)
    #pragma unroll
    for (int m = 0; m < 8; ++m) {
        int row = bm0 + ty * 8 + m;
        #pragma unroll
        for (int n = 0; n < 4; ++n) {
            int col = bn0 + tx * 4 + n;
            float r    = ma[m][n] - mb[m][n];
            float conc = fabsf(r) / 409.6f;
            float hc   = (r < 0.f) ? (1e-14f / conc) : conc;
            float ph   = (-logf(hc)) / 2.302585092994046f;
            out[(size_t)row * NOUT + col] = ph;
        }
    }
    #undef ISSUE_LOADS
    #undef WRITE_LDS
}

// Fallback (ws too small): R9's proven kernel with on-the-fly terms.
__global__ __launch_bounds__(256, 2) void acid_gemm_fly(const float* __restrict__ X,
                                                        const float* __restrict__ W,
                                                        float* __restrict__ out) {
    __shared__ float2 Asf[BK][BM + 1];
    __shared__ float  Bsf[BK][BN];
    const int tid = threadIdx.x;
    const int tx = tid & 15, ty = tid >> 4;
    const int bm0 = blockIdx.y * BM, bn0 = blockIdx.x * BN;
    float ma[8][4] = {}, mb[8][4] = {}, ca[8][4] = {}, cb[8][4] = {};
    for (int s = 0; s < NSTAGE; ++s) {
        const int k0 = s * BK;
        for (int idx = tid; idx < BM * BK; idx += 256) {
            int m = idx >> 5, k = idx & 31;
            Asf[k][m] = compute_terms(X[(size_t)(bm0 + m) * NIN + k0 + k]);
        }
        for (int idx = tid; idx < BK * BN; idx += 256) {
            int k = idx >> 6, c = idx & 63;
            Bsf[k][c] = signf_of(W[(size_t)(k0 + k) * NOUT + bn0 + c]);
        }
        __syncthreads();
        #pragma unroll 4
        for (int k = 0; k < BK; ++k) {
            float2 av[8]; float sv[4];
            #pragma unroll
            for (int m = 0; m < 8; ++m) av[m] = Asf[k][ty * 8 + m];
            #pragma unroll
            for (int n = 0; n < 4; ++n) sv[n] = Bsf[k][tx * 4 + n];
            #pragma unroll
            for (int m = 0; m < 8; ++m)
                #pragma unroll
                for (int n = 0; n < 4; ++n) {
                    ca[m][n] = fmaf(av[m].x, sv[n], ca[m][n]);
                    cb[m][n] = fmaf(av[m].y, sv[n], cb[m][n]);
                }
        }
        if (((s + 1) & 15) == 0) {
            #pragma unroll
            for (int m = 0; m < 8; ++m)
                #pragma unroll
                for (int n = 0; n < 4; ++n) {
                    ma[m][n] += ca[m][n]; ca[m][n] = 0.f;
                    mb[m][n] += cb[m][n]; cb[m][n] = 0.f;
                }
        }
        __syncthreads();
    }
    #pragma unroll
    for (int m = 0; m < 8; ++m) {
        int row = bm0 + ty * 8 + m;
        #pragma unroll
        for (int n = 0; n < 4; ++n) {
            int col = bn0 + tx * 4 + n;
            float r = ma[m][n] - mb[m][n];
            float conc = fabsf(r) / 409.6f;
            float hc = (r < 0.f) ? (1e-14f / conc) : conc;
            out[(size_t)row * NOUT + col] = (-logf(hc)) / 2.302585092994046f;
        }
    }
}

extern "C" void kernel_launch(void* const* d_in, const int* in_sizes, int n_in,
                              void* d_out, int out_size, void* d_ws, size_t ws_size,
                              hipStream_t stream) {
    const float* x = (const float*)d_in[0];
    const float* w = (const float*)d_in[1];
    float* out = (float*)d_out;

    const size_t needA = (size_t)BATCH * NIN * sizeof(float2);  // 134.2 MB
    dim3 grid(NOUT / BN, BATCH / BM);

    if (ws_size >= needA) {
        float2* a2 = (float2*)d_ws;
        precompute_terms<<<4096, 256, 0, stream>>>(x, a2, BATCH * NIN);
        acid_gemm_t14<<<grid, dim3(256), 0, stream>>>(a2, w, out);
    } else {
        acid_gemm_fly<<<grid, dim3(256), 0, stream>>>(x, w, out);
    }
}